// Round 6
// baseline (1181.342 us; speedup 1.0000x reference)
//
#include <hip/hip_runtime.h>
#include <hip/hip_bf16.h>

typedef __bf16 bf16;
typedef __attribute__((ext_vector_type(8))) __bf16 bf16x8;
typedef __attribute__((ext_vector_type(4))) float f32x4;

#define MFMA16(a, b, c) __builtin_amdgcn_mfma_f32_16x16x32_bf16((a), (b), (c), 0, 0, 0)

constexpr int Bc = 2, Sc = 2048, Dc = 1024, Hc = 16, DKc = 64, Ec = 1024;

// ---------------- f32 -> bf16 conversion ----------------
__global__ __launch_bounds__(256) void cvt_f32_bf16_k(const float* __restrict__ in,
                                                      bf16* __restrict__ out, int n4) {
  int i = blockIdx.x * 256 + threadIdx.x;
  if (i >= n4) return;
  const float4 v = reinterpret_cast<const float4*>(in)[i];
  alignas(8) bf16 t[4] = {(bf16)v.x, (bf16)v.y, (bf16)v.z, (bf16)v.w};
  reinterpret_cast<uint2*>(out)[i] = *reinterpret_cast<uint2*>(t);
}

__global__ __launch_bounds__(256) void cvt_kv_k(const float* __restrict__ a,
                                                const float* __restrict__ b,
                                                const int* __restrict__ flag,
                                                bf16* __restrict__ out, int n4) {
  int i = blockIdx.x * 256 + threadIdx.x;
  if (i >= n4) return;
  const float* src = (*flag != 0) ? b : a;
  const float4 v = reinterpret_cast<const float4*>(src)[i];
  alignas(8) bf16 t[4] = {(bf16)v.x, (bf16)v.y, (bf16)v.z, (bf16)v.w};
  reinterpret_cast<uint2*>(out)[i] = *reinterpret_cast<uint2*>(t);
}

// ---------------- QKV projection: out[r,e] = sum_d A[r,d] * W[e,d] ----------------
// grid (M/64, N/16, 3), block 256. Wave computes one 16x16 tile.
// C/D layout (verified m89): col = lane&15, row = (lane>>4)*4 + reg.
// A frag: row = lane&15, k = (lane>>4)*8 + j.  B frag: col(n) = lane&15, k = (lane>>4)*8 + j.
__global__ __launch_bounds__(256) void proj_qkv_k(const bf16* __restrict__ hb,
                                                  const bf16* __restrict__ kvb,
                                                  const bf16* __restrict__ wqb,
                                                  const bf16* __restrict__ wkb,
                                                  const bf16* __restrict__ wvb,
                                                  bf16* __restrict__ Qo,
                                                  bf16* __restrict__ Ko,
                                                  bf16* __restrict__ Vto) {
  const int sel = blockIdx.z;
  const bf16* __restrict__ A = (sel == 0) ? hb : kvb;
  const bf16* __restrict__ W = (sel == 0) ? wqb : (sel == 1 ? wkb : wvb);
  const int wave = threadIdx.x >> 6;
  const int lane = threadIdx.x & 63;
  const int lr = lane & 15;
  const int lg = lane >> 4;
  const int row0 = blockIdx.x * 64 + wave * 16;
  const int col0 = blockIdx.y * 16;

  const bf16* ap = A + (size_t)(row0 + lr) * 1024 + lg * 8;
  const bf16* wp = W + (size_t)(col0 + lr) * 1024 + lg * 8;
  f32x4 acc = {0.f, 0.f, 0.f, 0.f};
#pragma unroll 8
  for (int kk = 0; kk < 1024; kk += 32) {
    bf16x8 af = *reinterpret_cast<const bf16x8*>(ap + kk);
    bf16x8 bfr = *reinterpret_cast<const bf16x8*>(wp + kk);
    acc = MFMA16(af, bfr, acc);
  }
#pragma unroll
  for (int r = 0; r < 4; ++r) {
    const int row = row0 + lg * 4 + r;  // global row in [0, B*S)
    const int col = col0 + lr;          // e in [0, 1024)
    const int b = row >> 11, s = row & 2047;
    const int h = col >> 6, dk = col & 63;
    const bf16 v = (bf16)acc[r];
    if (sel == 0)
      Qo[(((size_t)(b * Hc + h) * Sc) + s) * DKc + dk] = v;
    else if (sel == 1)
      Ko[(((size_t)(b * Hc + h) * Sc) + s) * DKc + dk] = v;
    else
      Vto[(((size_t)(b * Hc + h) * DKc) + dk) * Sc + s] = v;  // V transposed
  }
}

// ---------------- Output projection: out[r,d] = sum_e ctx[r,e] * wo[d,e] ----------------
__global__ __launch_bounds__(256) void proj_out_k(const bf16* __restrict__ ctx,
                                                  const bf16* __restrict__ wob,
                                                  float* __restrict__ out) {
  const int wave = threadIdx.x >> 6;
  const int lane = threadIdx.x & 63;
  const int lr = lane & 15;
  const int lg = lane >> 4;
  const int row0 = blockIdx.x * 64 + wave * 16;
  const int col0 = blockIdx.y * 16;

  const bf16* ap = ctx + (size_t)(row0 + lr) * 1024 + lg * 8;
  const bf16* wp = wob + (size_t)(col0 + lr) * 1024 + lg * 8;
  f32x4 acc = {0.f, 0.f, 0.f, 0.f};
#pragma unroll 8
  for (int kk = 0; kk < 1024; kk += 32) {
    bf16x8 af = *reinterpret_cast<const bf16x8*>(ap + kk);
    bf16x8 bfr = *reinterpret_cast<const bf16x8*>(wp + kk);
    acc = MFMA16(af, bfr, acc);
  }
#pragma unroll
  for (int r = 0; r < 4; ++r) {
    const int row = row0 + lg * 4 + r;
    const int col = col0 + lr;
    out[(size_t)row * 1024 + col] = acc[r];
  }
}

// ---------------- Flash attention ----------------
// grid (S/64, H, B), block 256 (4 waves). Each wave: 16 q-rows, full K loop in steps of 32.
__global__ __launch_bounds__(256) void attn_k(const bf16* __restrict__ Q,
                                              const bf16* __restrict__ K,
                                              const bf16* __restrict__ Vt,
                                              const float* __restrict__ bias,
                                              bf16* __restrict__ ctx) {
  const int qb = blockIdx.x;
  const int h = blockIdx.y;
  const int b = blockIdx.z;
  const int wave = threadIdx.x >> 6;
  const int lane = threadIdx.x & 63;
  const int lr = lane & 15;
  const int lg = lane >> 4;
  const int bh = b * Hc + h;
  const int qr0 = qb * 64 + wave * 16;

  const bf16* Qp = Q + ((size_t)bh * Sc + qr0) * DKc;
  const bf16* Kp = K + (size_t)bh * Sc * DKc;
  const bf16* Vp = Vt + (size_t)bh * DKc * Sc;
  const float* bp = bias + ((size_t)h * Sc + qr0) * Sc;

  __shared__ __align__(16) bf16 Pl[4][16][32];

  const bf16x8 qf0 = *reinterpret_cast<const bf16x8*>(Qp + lr * DKc + lg * 8);
  const bf16x8 qf1 = *reinterpret_cast<const bf16x8*>(Qp + lr * DKc + lg * 8 + 32);

  f32x4 acc[4];
  float m[4], l[4];
#pragma unroll
  for (int r = 0; r < 4; ++r) {
    acc[r] = (f32x4){0.f, 0.f, 0.f, 0.f};
    m[r] = -1e30f;
    l[r] = 0.f;
  }

  for (int kt = 0; kt < Sc; kt += 32) {
    // S = Q K^T for two 16-wide kpos sub-tiles
    f32x4 s0 = {0.f, 0.f, 0.f, 0.f}, s1 = {0.f, 0.f, 0.f, 0.f};
    {
      const bf16* kp0 = Kp + (size_t)(kt + lr) * DKc + lg * 8;
      bf16x8 k00 = *reinterpret_cast<const bf16x8*>(kp0);
      bf16x8 k01 = *reinterpret_cast<const bf16x8*>(kp0 + 32);
      s0 = MFMA16(qf0, k00, s0);
      s0 = MFMA16(qf1, k01, s0);
      const bf16* kp1 = kp0 + 16 * DKc;
      bf16x8 k10 = *reinterpret_cast<const bf16x8*>(kp1);
      bf16x8 k11 = *reinterpret_cast<const bf16x8*>(kp1 + 32);
      s1 = MFMA16(qf0, k10, s1);
      s1 = MFMA16(qf1, k11, s1);
    }
    // add bias (f32), online softmax stats
    float sv0[4], sv1[4];
#pragma unroll
    for (int r = 0; r < 4; ++r) {
      const size_t rowoff = (size_t)(lg * 4 + r) * Sc;
      sv0[r] = s0[r] + bp[rowoff + kt + lr];
      sv1[r] = s1[r] + bp[rowoff + kt + 16 + lr];
    }
    float mx[4];
#pragma unroll
    for (int r = 0; r < 4; ++r) mx[r] = fmaxf(sv0[r], sv1[r]);
#pragma unroll
    for (int d = 1; d < 16; d <<= 1)
#pragma unroll
      for (int r = 0; r < 4; ++r) mx[r] = fmaxf(mx[r], __shfl_xor(mx[r], d));
    float alpha[4];
#pragma unroll
    for (int r = 0; r < 4; ++r) {
      const float mn = fmaxf(m[r], mx[r]);
      alpha[r] = __expf(m[r] - mn);
      m[r] = mn;
    }
    float p0[4], p1[4], ps[4];
#pragma unroll
    for (int r = 0; r < 4; ++r) {
      p0[r] = __expf(sv0[r] - m[r]);
      p1[r] = __expf(sv1[r] - m[r]);
      ps[r] = p0[r] + p1[r];
    }
#pragma unroll
    for (int d = 1; d < 16; d <<= 1)
#pragma unroll
      for (int r = 0; r < 4; ++r) ps[r] += __shfl_xor(ps[r], d);
#pragma unroll
    for (int r = 0; r < 4; ++r) l[r] = l[r] * alpha[r] + ps[r];
#pragma unroll
    for (int dt = 0; dt < 4; ++dt)
#pragma unroll
      for (int r = 0; r < 4; ++r) acc[dt][r] *= alpha[r];

    // stage P (bf16) to LDS for A-fragment transpose
    __syncthreads();
#pragma unroll
    for (int r = 0; r < 4; ++r) {
      Pl[wave][lg * 4 + r][lr] = (bf16)p0[r];
      Pl[wave][lg * 4 + r][16 + lr] = (bf16)p1[r];
    }
    __syncthreads();
    const bf16x8 pa = *reinterpret_cast<const bf16x8*>(&Pl[wave][lr][lg * 8]);
#pragma unroll
    for (int dt = 0; dt < 4; ++dt) {
      const bf16* vp = Vp + (size_t)(dt * 16 + lr) * Sc + kt + lg * 8;
      bf16x8 vb = *reinterpret_cast<const bf16x8*>(vp);
      acc[dt] = MFMA16(pa, vb, acc[dt]);
    }
  }

  // epilogue: normalize, store ctx[b, q, h*DK + d] bf16
#pragma unroll
  for (int dt = 0; dt < 4; ++dt) {
#pragma unroll
    for (int r = 0; r < 4; ++r) {
      const int q = qr0 + lg * 4 + r;
      const int dcol = dt * 16 + lr;
      const float val = acc[dt][r] / l[r];
      ctx[((size_t)(b * Sc + q)) * Ec + h * DKc + dcol] = (bf16)val;
    }
  }
}

extern "C" void kernel_launch(void* const* d_in, const int* in_sizes, int n_in,
                              void* d_out, int out_size, void* d_ws, size_t ws_size,
                              hipStream_t stream) {
  (void)in_sizes; (void)n_in; (void)out_size;
  const float* hidden = (const float*)d_in[0];
  // d_in[1] = attention_mask: unused by reference
  const float* pbias = (const float*)d_in[2];
  const float* kvs   = (const float*)d_in[3];
  const float* wq    = (const float*)d_in[4];
  const float* wk    = (const float*)d_in[5];
  const float* wv    = (const float*)d_in[6];
  const float* wo    = (const float*)d_in[7];
  const int* isdec   = (const int*)d_in[8];
  float* out = (float*)d_out;

  // Scratch: 28 M bf16 elements = 56 MB. Use d_ws only if provably large
  // enough; otherwise use the position_bias tail of d_out (268 MB), which is
  // overwritten last by the bias passthrough copy — every intermediate is
  // produced and consumed before that copy runs (stream-ordered). Branch is
  // launch-invariant, so graph capture sees identical work every call.
  const size_t SCRATCH_ELEMS = (size_t)28 * 1024 * 1024;
  bf16* scratch;
  if (ws_size >= SCRATCH_ELEMS * sizeof(bf16))
    scratch = (bf16*)d_ws;
  else
    scratch = (bf16*)(out + (size_t)Bc * Sc * Dc);  // bias region of d_out

  bf16* hb   = scratch;                          // 4M elems
  bf16* kvb  = hb  + (size_t)4 * 1024 * 1024;    // 4M
  bf16* wqb  = kvb + (size_t)4 * 1024 * 1024;    // 1M
  bf16* wkb  = wqb + (size_t)1024 * 1024;
  bf16* wvb  = wkb + (size_t)1024 * 1024;
  bf16* wob  = wvb + (size_t)1024 * 1024;
  bf16* Qw   = wob + (size_t)1024 * 1024;        // 4M
  bf16* Kw   = Qw  + (size_t)4 * 1024 * 1024;    // 4M
  bf16* Vtw  = Kw  + (size_t)4 * 1024 * 1024;    // 4M
  bf16* ctxw = Vtw + (size_t)4 * 1024 * 1024;    // 4M  (total 28M elems = 56 MB)

  cvt_f32_bf16_k<<<4096, 256, 0, stream>>>(hidden, hb, 1048576);
  cvt_kv_k<<<4096, 256, 0, stream>>>(hidden, kvs, isdec, kvb, 1048576);
  cvt_f32_bf16_k<<<1024, 256, 0, stream>>>(wq, wqb, 262144);
  cvt_f32_bf16_k<<<1024, 256, 0, stream>>>(wk, wkb, 262144);
  cvt_f32_bf16_k<<<1024, 256, 0, stream>>>(wv, wvb, 262144);
  cvt_f32_bf16_k<<<1024, 256, 0, stream>>>(wo, wob, 262144);

  proj_qkv_k<<<dim3(64, 64, 3), 256, 0, stream>>>(hb, kvb, wqb, wkb, wvb, Qw, Kw, Vtw);
  attn_k<<<dim3(Sc / 64, Hc, Bc), 256, 0, stream>>>(Qw, Kw, Vtw, pbias, ctxw);
  proj_out_k<<<dim3(64, 64), 256, 0, stream>>>(ctxw, wob, out);

  // second tuple output: position_bias passthrough (256 MB d2d copy) — LAST,
  // so it may legally overwrite the d_out-tail scratch region.
  hipMemcpyAsync(out + (size_t)Bc * Sc * Dc, pbias,
                 (size_t)Hc * Sc * Sc * sizeof(float), hipMemcpyDeviceToDevice, stream);
}

// Round 8
// 809.111 us; speedup vs baseline: 1.4600x; 1.4600x over previous
//
#include <hip/hip_runtime.h>
#include <hip/hip_bf16.h>

typedef __bf16 bf16;
typedef __attribute__((ext_vector_type(8))) __bf16 bf16x8;
typedef __attribute__((ext_vector_type(4))) float f32x4;

#define MFMA16(a, b, c) __builtin_amdgcn_mfma_f32_16x16x32_bf16((a), (b), (c), 0, 0, 0)

constexpr int Bc = 2, Sc = 2048, Dc = 1024, Hc = 16, DKc = 64, Ec = 1024;

// ==================== 128x128 LDS-tiled GEMM-BT projections ====================
// C[m,n] = sum_k A[m,k] * W[n,k].  M=4096, N=1024, K=1024. BM=BN=128, BK=32.
// Block: 256 thr = 4 waves in 2x2; wave computes 64x64 = 4x4 frags of 16x16x32.
// Staging: reg-staged (fuses f32->bf16 conversion), 2 barriers per K-step.
// Frag maps (verified m89): A row=lane&15, k=(lane>>4)*8+j; B col=lane&15, same k;
// C/D col=lane&15, row=(lane>>4)*4+reg.

__global__ __launch_bounds__(256) void proj_qkv_k(const float* __restrict__ hidden,
                                                  const float* __restrict__ kvs,
                                                  const int* __restrict__ flag,
                                                  const float* __restrict__ wq,
                                                  const float* __restrict__ wk,
                                                  const float* __restrict__ wv,
                                                  bf16* __restrict__ Qo,
                                                  bf16* __restrict__ Ko,
                                                  bf16* __restrict__ Vto) {
  const int sel = blockIdx.z;
  const float* __restrict__ A =
      (sel == 0) ? hidden : ((*flag != 0) ? kvs : hidden);
  const float* __restrict__ W = (sel == 0) ? wq : (sel == 1 ? wk : wv);

  const int row0 = blockIdx.x * 128;
  const int col0 = blockIdx.y * 128;
  const int tid = threadIdx.x;
  const int wid = tid >> 6, lane = tid & 63;
  const int lr = lane & 15, lg = lane >> 4;
  const int wr = wid >> 1, wc = wid & 1;

  __shared__ __align__(16) bf16 As[128 * 32];  // [row][k] linear, 8 KB
  __shared__ __align__(16) bf16 Ws[128 * 32];

  f32x4 acc[4][4] = {};

  for (int kt = 0; kt < 1024; kt += 32) {
    __syncthreads();
#pragma unroll
    for (int rnd = 0; rnd < 2; ++rnd) {
      const int c = rnd * 256 + tid;          // 16B chunk id; LDS elem = c*8
      const int row = c >> 2, rb = (c & 3) * 8;
      const float4 fa0 = *reinterpret_cast<const float4*>(&A[(size_t)(row0 + row) * 1024 + kt + rb]);
      const float4 fa1 = *reinterpret_cast<const float4*>(&A[(size_t)(row0 + row) * 1024 + kt + rb + 4]);
      alignas(16) bf16 ta[8] = {(bf16)fa0.x, (bf16)fa0.y, (bf16)fa0.z, (bf16)fa0.w,
                                (bf16)fa1.x, (bf16)fa1.y, (bf16)fa1.z, (bf16)fa1.w};
      *reinterpret_cast<bf16x8*>(&As[c * 8]) = *reinterpret_cast<bf16x8*>(ta);
      const float4 fw0 = *reinterpret_cast<const float4*>(&W[(size_t)(col0 + row) * 1024 + kt + rb]);
      const float4 fw1 = *reinterpret_cast<const float4*>(&W[(size_t)(col0 + row) * 1024 + kt + rb + 4]);
      alignas(16) bf16 tw[8] = {(bf16)fw0.x, (bf16)fw0.y, (bf16)fw0.z, (bf16)fw0.w,
                                (bf16)fw1.x, (bf16)fw1.y, (bf16)fw1.z, (bf16)fw1.w};
      *reinterpret_cast<bf16x8*>(&Ws[c * 8]) = *reinterpret_cast<bf16x8*>(tw);
    }
    __syncthreads();
    bf16x8 af[4], wf[4];
#pragma unroll
    for (int m = 0; m < 4; ++m)
      af[m] = *reinterpret_cast<const bf16x8*>(&As[(wr * 64 + m * 16 + lr) * 32 + lg * 8]);
#pragma unroll
    for (int n = 0; n < 4; ++n)
      wf[n] = *reinterpret_cast<const bf16x8*>(&Ws[(wc * 64 + n * 16 + lr) * 32 + lg * 8]);
#pragma unroll
    for (int m = 0; m < 4; ++m)
#pragma unroll
      for (int n = 0; n < 4; ++n)
        acc[m][n] = MFMA16(af[m], wf[n], acc[m][n]);
  }

#pragma unroll
  for (int m = 0; m < 4; ++m)
#pragma unroll
    for (int n = 0; n < 4; ++n)
#pragma unroll
      for (int r = 0; r < 4; ++r) {
        const int row = row0 + wr * 64 + m * 16 + lg * 4 + r;  // [0, B*S)
        const int col = col0 + wc * 64 + n * 16 + lr;          // e in [0, 1024)
        const int b = row >> 11, s = row & 2047;
        const int h = col >> 6, dk = col & 63;
        const bf16 v = (bf16)acc[m][n][r];
        if (sel == 0)
          Qo[(((size_t)(b * Hc + h) * Sc) + s) * DKc + dk] = v;
        else if (sel == 1)
          Ko[(((size_t)(b * Hc + h) * Sc) + s) * DKc + dk] = v;
        else
          Vto[(((size_t)(b * Hc + h) * DKc) + dk) * Sc + s] = v;  // V transposed
      }
}

// ---------------- Output projection: out[r,d] = sum_e ctx[r,e] * wo[d,e] ----------------
__global__ __launch_bounds__(256) void proj_out_k(const bf16* __restrict__ ctx,
                                                  const float* __restrict__ wo,
                                                  float* __restrict__ out) {
  const int row0 = blockIdx.x * 128;
  const int col0 = blockIdx.y * 128;
  const int tid = threadIdx.x;
  const int wid = tid >> 6, lane = tid & 63;
  const int lr = lane & 15, lg = lane >> 4;
  const int wr = wid >> 1, wc = wid & 1;

  __shared__ __align__(16) bf16 As[128 * 32];
  __shared__ __align__(16) bf16 Ws[128 * 32];

  f32x4 acc[4][4] = {};

  for (int kt = 0; kt < 1024; kt += 32) {
    __syncthreads();
#pragma unroll
    for (int rnd = 0; rnd < 2; ++rnd) {
      const int c = rnd * 256 + tid;
      const int row = c >> 2, rb = (c & 3) * 8;
      // A (ctx) already bf16: straight 16B copy
      *reinterpret_cast<bf16x8*>(&As[c * 8]) =
          *reinterpret_cast<const bf16x8*>(&ctx[(size_t)(row0 + row) * 1024 + kt + rb]);
      const float4 fw0 = *reinterpret_cast<const float4*>(&wo[(size_t)(col0 + row) * 1024 + kt + rb]);
      const float4 fw1 = *reinterpret_cast<const float4*>(&wo[(size_t)(col0 + row) * 1024 + kt + rb + 4]);
      alignas(16) bf16 tw[8] = {(bf16)fw0.x, (bf16)fw0.y, (bf16)fw0.z, (bf16)fw0.w,
                                (bf16)fw1.x, (bf16)fw1.y, (bf16)fw1.z, (bf16)fw1.w};
      *reinterpret_cast<bf16x8*>(&Ws[c * 8]) = *reinterpret_cast<bf16x8*>(tw);
    }
    __syncthreads();
    bf16x8 af[4], wf[4];
#pragma unroll
    for (int m = 0; m < 4; ++m)
      af[m] = *reinterpret_cast<const bf16x8*>(&As[(wr * 64 + m * 16 + lr) * 32 + lg * 8]);
#pragma unroll
    for (int n = 0; n < 4; ++n)
      wf[n] = *reinterpret_cast<const bf16x8*>(&Ws[(wc * 64 + n * 16 + lr) * 32 + lg * 8]);
#pragma unroll
    for (int m = 0; m < 4; ++m)
#pragma unroll
      for (int n = 0; n < 4; ++n)
        acc[m][n] = MFMA16(af[m], wf[n], acc[m][n]);
  }

#pragma unroll
  for (int m = 0; m < 4; ++m)
#pragma unroll
    for (int n = 0; n < 4; ++n)
#pragma unroll
      for (int r = 0; r < 4; ++r) {
        const int row = row0 + wr * 64 + m * 16 + lg * 4 + r;
        const int col = col0 + wc * 64 + n * 16 + lr;
        out[(size_t)row * 1024 + col] = acc[m][n][r];
      }
}

// ---------------- Flash attention (unchanged from round 6 baseline) ----------------
// grid (S/64, H, B), block 256 (4 waves). Each wave: 16 q-rows, full K loop in steps of 32.
__global__ __launch_bounds__(256) void attn_k(const bf16* __restrict__ Q,
                                              const bf16* __restrict__ K,
                                              const bf16* __restrict__ Vt,
                                              const float* __restrict__ bias,
                                              bf16* __restrict__ ctx) {
  const int qb = blockIdx.x;
  const int h = blockIdx.y;
  const int b = blockIdx.z;
  const int wave = threadIdx.x >> 6;
  const int lane = threadIdx.x & 63;
  const int lr = lane & 15;
  const int lg = lane >> 4;
  const int bh = b * Hc + h;
  const int qr0 = qb * 64 + wave * 16;

  const bf16* Qp = Q + ((size_t)bh * Sc + qr0) * DKc;
  const bf16* Kp = K + (size_t)bh * Sc * DKc;
  const bf16* Vp = Vt + (size_t)bh * DKc * Sc;
  const float* bp = bias + ((size_t)h * Sc + qr0) * Sc;

  __shared__ __align__(16) bf16 Pl[4][16][32];

  const bf16x8 qf0 = *reinterpret_cast<const bf16x8*>(Qp + lr * DKc + lg * 8);
  const bf16x8 qf1 = *reinterpret_cast<const bf16x8*>(Qp + lr * DKc + lg * 8 + 32);

  f32x4 acc[4];
  float m[4], l[4];
#pragma unroll
  for (int r = 0; r < 4; ++r) {
    acc[r] = (f32x4){0.f, 0.f, 0.f, 0.f};
    m[r] = -1e30f;
    l[r] = 0.f;
  }

  for (int kt = 0; kt < Sc; kt += 32) {
    f32x4 s0 = {0.f, 0.f, 0.f, 0.f}, s1 = {0.f, 0.f, 0.f, 0.f};
    {
      const bf16* kp0 = Kp + (size_t)(kt + lr) * DKc + lg * 8;
      bf16x8 k00 = *reinterpret_cast<const bf16x8*>(kp0);
      bf16x8 k01 = *reinterpret_cast<const bf16x8*>(kp0 + 32);
      s0 = MFMA16(qf0, k00, s0);
      s0 = MFMA16(qf1, k01, s0);
      const bf16* kp1 = kp0 + 16 * DKc;
      bf16x8 k10 = *reinterpret_cast<const bf16x8*>(kp1);
      bf16x8 k11 = *reinterpret_cast<const bf16x8*>(kp1 + 32);
      s1 = MFMA16(qf0, k10, s1);
      s1 = MFMA16(qf1, k11, s1);
    }
    float sv0[4], sv1[4];
#pragma unroll
    for (int r = 0; r < 4; ++r) {
      const size_t rowoff = (size_t)(lg * 4 + r) * Sc;
      sv0[r] = s0[r] + bp[rowoff + kt + lr];
      sv1[r] = s1[r] + bp[rowoff + kt + 16 + lr];
    }
    float mx[4];
#pragma unroll
    for (int r = 0; r < 4; ++r) mx[r] = fmaxf(sv0[r], sv1[r]);
#pragma unroll
    for (int d = 1; d < 16; d <<= 1)
#pragma unroll
      for (int r = 0; r < 4; ++r) mx[r] = fmaxf(mx[r], __shfl_xor(mx[r], d));
    float alpha[4];
#pragma unroll
    for (int r = 0; r < 4; ++r) {
      const float mn = fmaxf(m[r], mx[r]);
      alpha[r] = __expf(m[r] - mn);
      m[r] = mn;
    }
    float p0[4], p1[4], ps[4];
#pragma unroll
    for (int r = 0; r < 4; ++r) {
      p0[r] = __expf(sv0[r] - m[r]);
      p1[r] = __expf(sv1[r] - m[r]);
      ps[r] = p0[r] + p1[r];
    }
#pragma unroll
    for (int d = 1; d < 16; d <<= 1)
#pragma unroll
      for (int r = 0; r < 4; ++r) ps[r] += __shfl_xor(ps[r], d);
#pragma unroll
    for (int r = 0; r < 4; ++r) l[r] = l[r] * alpha[r] + ps[r];
#pragma unroll
    for (int dt = 0; dt < 4; ++dt)
#pragma unroll
      for (int r = 0; r < 4; ++r) acc[dt][r] *= alpha[r];

    __syncthreads();
#pragma unroll
    for (int r = 0; r < 4; ++r) {
      Pl[wave][lg * 4 + r][lr] = (bf16)p0[r];
      Pl[wave][lg * 4 + r][16 + lr] = (bf16)p1[r];
    }
    __syncthreads();
    const bf16x8 pa = *reinterpret_cast<const bf16x8*>(&Pl[wave][lr][lg * 8]);
#pragma unroll
    for (int dt = 0; dt < 4; ++dt) {
      const bf16* vp = Vp + (size_t)(dt * 16 + lr) * Sc + kt + lg * 8;
      bf16x8 vb = *reinterpret_cast<const bf16x8*>(vp);
      acc[dt] = MFMA16(pa, vb, acc[dt]);
    }
  }

#pragma unroll
  for (int dt = 0; dt < 4; ++dt) {
#pragma unroll
    for (int r = 0; r < 4; ++r) {
      const int q = qr0 + lg * 4 + r;
      const int dcol = dt * 16 + lr;
      const float val = acc[dt][r] / l[r];
      ctx[((size_t)(b * Sc + q)) * Ec + h * DKc + dcol] = (bf16)val;
    }
  }
}

extern "C" void kernel_launch(void* const* d_in, const int* in_sizes, int n_in,
                              void* d_out, int out_size, void* d_ws, size_t ws_size,
                              hipStream_t stream) {
  (void)in_sizes; (void)n_in; (void)out_size;
  const float* hidden = (const float*)d_in[0];
  // d_in[1] = attention_mask: unused by reference
  const float* pbias = (const float*)d_in[2];
  const float* kvs   = (const float*)d_in[3];
  const float* wq    = (const float*)d_in[4];
  const float* wk    = (const float*)d_in[5];
  const float* wv    = (const float*)d_in[6];
  const float* wo    = (const float*)d_in[7];
  const int* isdec   = (const int*)d_in[8];
  float* out = (float*)d_out;

  // Scratch: 16 M bf16 elements = 32 MB (Q, K, Vt, ctx). Use d_ws if large
  // enough; else the position_bias tail of d_out (overwritten last by the
  // passthrough copy; all intermediates produced+consumed before it).
  const size_t SCRATCH_ELEMS = (size_t)16 * 1024 * 1024;
  bf16* scratch;
  if (ws_size >= SCRATCH_ELEMS * sizeof(bf16))
    scratch = (bf16*)d_ws;
  else
    scratch = (bf16*)(out + (size_t)Bc * Sc * Dc);  // bias region of d_out

  bf16* Qw   = scratch;                          // 4M elems
  bf16* Kw   = Qw  + (size_t)4 * 1024 * 1024;    // 4M
  bf16* Vtw  = Kw  + (size_t)4 * 1024 * 1024;    // 4M
  bf16* ctxw = Vtw + (size_t)4 * 1024 * 1024;    // 4M  (total 16M elems = 32 MB)

  proj_qkv_k<<<dim3(32, 8, 3), 256, 0, stream>>>(hidden, kvs, isdec, wq, wk, wv,
                                                 Qw, Kw, Vtw);
  attn_k<<<dim3(Sc / 64, Hc, Bc), 256, 0, stream>>>(Qw, Kw, Vtw, pbias, ctxw);
  proj_out_k<<<dim3(32, 8), 256, 0, stream>>>(ctxw, wo, out);

  // second tuple output: position_bias passthrough (256 MB d2d copy) — LAST,
  // so it may legally overwrite the d_out-tail scratch region.
  hipMemcpyAsync(out + (size_t)Bc * Sc * Dc, pbias,
                 (size_t)Hc * Sc * Sc * sizeof(float), hipMemcpyDeviceToDevice, stream);
}